// Round 13
// baseline (723.594 us; speedup 1.0000x reference)
//
#include <hip/hip_runtime.h>
#include <hip/hip_bf16.h>
#include <cstdint>

// MoRALinear: out[m,o] = sum_i x[m,i] * (W[o,i] + A[o&1023, i&1023]) + b[o]
// R12: R9 skeleton (256x256, BK=32, 8-wave 2Mx4N, mfma_32x32x16,
//      fragment-major panels, kh-level reg double-buffer, SGB interleave,
//      1 barrier/K-tile) with B READ DIRECTLY GLOBAL->REG (no LDS for B):
//      deletes 48 KB/K-tile of LDS-port traffic (32 KB B ds_reads + 16 KB
//      B DMA writes). B prefetched one K-tile ahead into named reg sets;
//      nb-major XCD chunking keeps B panels L2-resident. A stays in a
//      4-slot LDS ring (64 KB). No launch_bounds cap (VGPR ~205; R10
//      evidence: 2nd arg is min blocks/CU and caps VGPR).

typedef __attribute__((ext_vector_type(8))) short bf16x8;
typedef __attribute__((ext_vector_type(16))) float f32x16;
typedef __attribute__((ext_vector_type(4))) float fvec4;

static constexpr int MTOT = 16384;   // B*S
static constexpr int KF   = 4096;    // IN_F
static constexpr int NF   = 4096;    // OUT_F
static constexpr int BM = 256, BN = 256, BK = 32;
static constexpr int TILE = BM * BK;          // 8192 bf16 elems per K-tile panel
static constexpr int KT = KF / BK;            // 128 K-tiles
static constexpr int MB = MTOT / BM;          // 64
static constexpr int NB = NF / BN;            // 16

// ---------------- prep: x -> bf16, fragment-major (32x32x16 frags) -----------
__global__ __launch_bounds__(256) void tile_x_kernel(const float* __restrict__ x,
                                                     __hip_bfloat16* __restrict__ xt) {
    int blk = blockIdx.x;               // mb*KT + kt ; grid = 64*128
    int mb = blk >> 7, kt = blk & 127;
    int tid = threadIdx.x;
    __hip_bfloat16* dst = xt + (size_t)blk * TILE;
#pragma unroll
    for (int it = 0; it < 4; ++it) {
        int e = (it * 256 + tid) * 8;   // element within tile, 0..8191
        int f = e >> 9;                 // fragment 0..15
        int l = (e >> 3) & 63;          // lane 0..63
        int rb = f >> 1, kh = f & 1;
        int row = mb * BM + rb * 32 + (l & 31);
        int k0  = kt * BK + kh * 16 + (l >> 5) * 8;
        const fvec4* s = (const fvec4*)(x + (size_t)row * KF + k0);
        fvec4 v0 = s[0], v1 = s[1];
        union { bf16x8 v; __hip_bfloat16 h[8]; } o;
        o.h[0] = __float2bfloat16(v0[0]); o.h[1] = __float2bfloat16(v0[1]);
        o.h[2] = __float2bfloat16(v0[2]); o.h[3] = __float2bfloat16(v0[3]);
        o.h[4] = __float2bfloat16(v1[0]); o.h[5] = __float2bfloat16(v1[1]);
        o.h[6] = __float2bfloat16(v1[2]); o.h[7] = __float2bfloat16(v1[3]);
        *(bf16x8*)(dst + e) = o.v;
    }
}

// ---------------- prep: W' = W + tiled(A) -> bf16 fragment-major -------------
__global__ __launch_bounds__(256) void tile_w_kernel(const float* __restrict__ W,
                                                     const float* __restrict__ A,
                                                     __hip_bfloat16* __restrict__ wt) {
    int blk = blockIdx.x;               // nb*KT + kt ; grid = 16*128
    int nb = blk >> 7, kt = blk & 127;
    int tid = threadIdx.x;
    __hip_bfloat16* dst = wt + (size_t)blk * TILE;
#pragma unroll
    for (int it = 0; it < 4; ++it) {
        int e = (it * 256 + tid) * 8;
        int f = e >> 9;
        int l = (e >> 3) & 63;
        int rb = f >> 1, kh = f & 1;
        int o  = nb * BN + rb * 32 + (l & 31);
        int k0 = kt * BK + kh * 16 + (l >> 5) * 8;
        const fvec4* sw = (const fvec4*)(W + (size_t)o * KF + k0);
        const fvec4* sa = (const fvec4*)(A + (size_t)(o & 1023) * 1024 + (k0 & 1023));
        fvec4 w0 = sw[0], w1 = sw[1];
        fvec4 a0 = sa[0], a1 = sa[1];
        union { bf16x8 v; __hip_bfloat16 h[8]; } ov;
        ov.h[0] = __float2bfloat16(w0[0] + a0[0]); ov.h[1] = __float2bfloat16(w0[1] + a0[1]);
        ov.h[2] = __float2bfloat16(w0[2] + a0[2]); ov.h[3] = __float2bfloat16(w0[3] + a0[3]);
        ov.h[4] = __float2bfloat16(w1[0] + a1[0]); ov.h[5] = __float2bfloat16(w1[1] + a1[1]);
        ov.h[6] = __float2bfloat16(w1[2] + a1[2]); ov.h[7] = __float2bfloat16(w1[3] + a1[3]);
        *(bf16x8*)(dst + e) = ov.v;
    }
}

// ---------------- async global->LDS (width 16) ----------------
__device__ inline void gload_lds16(const __hip_bfloat16* g, __hip_bfloat16* l) {
    __builtin_amdgcn_global_load_lds(
        (const __attribute__((address_space(1))) unsigned int*)g,
        (__attribute__((address_space(3))) unsigned int*)l, 16, 0, 0);
}

// stage one A K-tile (16 KB) = 2 gloads per thread
#define STG_A(tt, sl) { const __hip_bfloat16* ga_ = aP + (size_t)(tt) * TILE + t8; \
    gload_lds16(ga_, As + (sl) * TILE + t8);                                     \
    gload_lds16(ga_ + 4096, As + (sl) * TILE + 4096 + t8); }

// load one K-tile's B fragments global->reg (4 x global_load_dwordx4)
// P##0 = (kh0,fn0), P##1 = (kh0,fn1), P##2 = (kh1,fn0), P##3 = (kh1,fn1)
#define BLD(P, tt) { const __hip_bfloat16* gb_ = bP + (size_t)(tt) * TILE + bOff; \
    P##0 = *(const bf16x8*)(gb_);                                                \
    P##1 = *(const bf16x8*)(gb_ + 1024);                                         \
    P##2 = *(const bf16x8*)(gb_ + 512);                                          \
    P##3 = *(const bf16x8*)(gb_ + 1536); }

// read one kh-set of A (4 ds_read_b128, frag-major: base + lane*16B)
#define RD_A(P, SL, KH) { const __hip_bfloat16* ab_ = As + (SL) * TILE + aOff + (KH) * 512; \
    P##0 = *(const bf16x8*)(ab_);                                                \
    P##1 = *(const bf16x8*)(ab_ + 1024);                                         \
    P##2 = *(const bf16x8*)(ab_ + 2048);                                         \
    P##3 = *(const bf16x8*)(ab_ + 3072); }

// 8 MFMAs: one kh-slice, A-set P x B-frags (Bx = fn0, By = fn1)
#define MM8(P, Bx, By) {                                                         \
    acc[0][0] = __builtin_amdgcn_mfma_f32_32x32x16_bf16(P##0, Bx, acc[0][0], 0, 0, 0); \
    acc[0][1] = __builtin_amdgcn_mfma_f32_32x32x16_bf16(P##0, By, acc[0][1], 0, 0, 0); \
    acc[1][0] = __builtin_amdgcn_mfma_f32_32x32x16_bf16(P##1, Bx, acc[1][0], 0, 0, 0); \
    acc[1][1] = __builtin_amdgcn_mfma_f32_32x32x16_bf16(P##1, By, acc[1][1], 0, 0, 0); \
    acc[2][0] = __builtin_amdgcn_mfma_f32_32x32x16_bf16(P##2, Bx, acc[2][0], 0, 0, 0); \
    acc[2][1] = __builtin_amdgcn_mfma_f32_32x32x16_bf16(P##2, By, acc[2][1], 0, 0, 0); \
    acc[3][0] = __builtin_amdgcn_mfma_f32_32x32x16_bf16(P##3, Bx, acc[3][0], 0, 0, 0); \
    acc[3][1] = __builtin_amdgcn_mfma_f32_32x32x16_bf16(P##3, By, acc[3][1], 0, 0, 0); }

#define SGB(m, n) __builtin_amdgcn_sched_group_barrier((m), (n), 0)

// one K-tile step: 6 VMEM (4 B-loads + 2 A-stage), 8 DS_READ, 16 MFMA.
// SGB pins: all VMEM early, then (DS 1, MFMA 2) x 8. Reads are independent
// of this step's MFMAs (reg-dbuf). vmcnt(0)+barrier: A(t+2) resident and
// B(t+1) regs valid for next step (compiler also auto-waits B uses).
#define STEP(tt, SL, BCUR, BNXT) {                                               \
    int tn_ = (tt) + 1; if (tn_ >= KT) tn_ = 0;   /* tail clamp, data unused */  \
    int ts_ = (tt) + 2; if (ts_ >= KT) ts_ = 0;                                  \
    BLD(BNXT, tn_)                                                               \
    STG_A(ts_, ((SL) + 2) & 3)                                                   \
    RD_A(S2, SL, 1)                   /* A(t, kh1)   */                          \
    MM8(S1, BCUR##0, BCUR##1)         /* mfma (t,kh0) */                         \
    RD_A(S1, ((SL) + 1) & 3, 0)       /* A(t+1, kh0) */                          \
    MM8(S2, BCUR##2, BCUR##3)         /* mfma (t,kh1) */                         \
    SGB(0x30, 6);                                                                \
    SGB(0x100, 1); SGB(0x8, 2); SGB(0x100, 1); SGB(0x8, 2);                      \
    SGB(0x100, 1); SGB(0x8, 2); SGB(0x100, 1); SGB(0x8, 2);                      \
    SGB(0x100, 1); SGB(0x8, 2); SGB(0x100, 1); SGB(0x8, 2);                      \
    SGB(0x100, 1); SGB(0x8, 2); SGB(0x100, 1); SGB(0x8, 2);                      \
    asm volatile("s_waitcnt vmcnt(0)" ::: "memory");                             \
    __builtin_amdgcn_s_barrier();                                                \
    __builtin_amdgcn_sched_barrier(0);                                           \
    asm volatile("" ::: "memory"); }

__global__ __launch_bounds__(512) void gemm_bf16_kernel(
    const __hip_bfloat16* __restrict__ xt, const __hip_bfloat16* __restrict__ wt,
    const float* __restrict__ bias, float* __restrict__ out) {
    extern __shared__ __hip_bfloat16 lds[];
    __hip_bfloat16* As = lds;                 // 4 slots * 8192 elems (64 KB)

    // XCD chunking, nb-major inside chunk: each XCD works on 2 B-panels
    // (2 x 2 MB, L2-resident) -> direct B reads hit L2.
    int bid = blockIdx.x;                     // nwg = 1024
    int wg = (bid & 7) * 128 + (bid >> 3);
    int nb = wg >> 6;                         // 16 col-blocks
    int mb = wg & 63;                         // 64 row-blocks

    int tid = threadIdx.x;
    int lane = tid & 63;
    int wv = tid >> 6;                        // 8 waves
    int wm = wv >> 2, wn = wv & 3;            // 2 x 4 wave grid, 128x64 C each
    int t8 = tid * 8;

    // A frag (fm, kh): LDS off = wm*4096 + fm*1024 + kh*512 + lane*8
    // B frag (fn, kh): global off = wn*2048 + fn*1024 + kh*512 + lane*8
    int aOff = wm * 4096 + lane * 8;
    int bOff = wn * 2048 + lane * 8;

    const __hip_bfloat16* aP = xt + (size_t)mb * (KT * TILE);
    const __hip_bfloat16* bP = wt + (size_t)nb * (KT * TILE);

    f32x16 acc[4][2];
#pragma unroll
    for (int fm = 0; fm < 4; ++fm)
#pragma unroll
        for (int fn = 0; fn < 2; ++fn)
#pragma unroll
            for (int r = 0; r < 16; ++r) acc[fm][fn][r] = 0.f;

    bf16x8 S10, S11, S12, S13, S20, S21, S22, S23;   // A kh-sets (static names)
    bf16x8 Bc0, Bc1, Bc2, Bc3, Bn0, Bn1, Bn2, Bn3;   // B tile-sets (static names)

    // prologue: A tiles 0,1 -> slots 0,1; B tile 0 -> Bc; drain; prime A(0,kh0)
    STG_A(0, 0) STG_A(1, 1)
    BLD(Bc, 0)
    asm volatile("s_waitcnt vmcnt(0)" ::: "memory");
    __builtin_amdgcn_s_barrier();
    asm volatile("" ::: "memory");
    RD_A(S1, 0, 0)

    // main loop: step t computes K-tile t (A slot t&3, B set parity t&1),
    // stages A(t+2), loads B(t+1), pre-reads A(t+1,kh0).
    for (int j = 0; j < KT / 4; ++j) {
        int tb = 4 * j;
        STEP(tb + 0, 0, Bc, Bn)
        STEP(tb + 1, 1, Bn, Bc)
        STEP(tb + 2, 2, Bc, Bn)
        STEP(tb + 3, 3, Bn, Bc)
    }
    // last step's vmcnt(0) drained all DMA; nothing in flight here.

    // epilogue: 32x32 C/D layout: col = lane&31, row = (reg&3)+8*(reg>>2)+4*(lane>>5)
    int row0 = mb * BM + wm * 128;
    int col0 = nb * BN + wn * 64;
    int ln31 = lane & 31;
    int l5 = lane >> 5;
#pragma unroll
    for (int fn = 0; fn < 2; ++fn) {
        int col = col0 + fn * 32 + ln31;
        float bv = bias[col];
#pragma unroll
        for (int fm = 0; fm < 4; ++fm) {
            int rbase = row0 + fm * 32 + 4 * l5;
#pragma unroll
            for (int r = 0; r < 16; ++r) {
                int row = rbase + (r & 3) + 8 * (r >> 2);
                out[(size_t)row * NF + col] = acc[fm][fn][r] + bv;
            }
        }
    }
}

extern "C" void kernel_launch(void* const* d_in, const int* in_sizes, int n_in,
                              void* d_out, int out_size, void* d_ws, size_t ws_size,
                              hipStream_t stream) {
    const float* x = (const float*)d_in[0];
    const float* W = (const float*)d_in[1];
    const float* b = (const float*)d_in[2];
    const float* A = (const float*)d_in[3];
    float* out = (float*)d_out;

    size_t xt_elems = (size_t)MB * KT * TILE;       // 67.1M elems
    size_t wt_elems = (size_t)NB * KT * TILE;       // 16.8M elems
    size_t need = (xt_elems + wt_elems) * sizeof(__hip_bfloat16);
    if (ws_size < need) return;

    __hip_bfloat16* xt = (__hip_bfloat16*)d_ws;
    __hip_bfloat16* wt = xt + xt_elems;

    (void)hipFuncSetAttribute((const void*)gemm_bf16_kernel,
                              hipFuncAttributeMaxDynamicSharedMemorySize, 65536);

    tile_x_kernel<<<MB * KT, 256, 0, stream>>>(x, xt);
    tile_w_kernel<<<NB * KT, 256, 0, stream>>>(W, A, wt);
    gemm_bf16_kernel<<<MB * NB, 512, 65536, stream>>>(xt, wt, b, out);
}

// Round 16
// 598.781 us; speedup vs baseline: 1.2084x; 1.2084x over previous
//
#include <hip/hip_runtime.h>
#include <hip/hip_bf16.h>
#include <cstdint>

// MoRALinear: out[m,o] = sum_i x[m,i] * (W[o,i] + A[o&1023, i&1023]) + b[o]
// R15: R9 base (256x256, BK=32, 8-wave, 4-slot ring = 128 KiB LDS (!),
//      mfma_32x32x16, fragment-major panels, kh-level reg double-buffer,
//      counted vmcnt(4), 1 barrier/K-tile, SGB interleave) + WAVE-GROUP
//      PHASE STAGGER (wm=0 read-leading, wm=1 MFMA-leading). R13/R14 failed
//      ONLY because dynamic LDS was launched at 65536 while the layout needs
//      131072 -> B slots out of bounds. Fixed here.

typedef __attribute__((ext_vector_type(8))) short bf16x8;
typedef __attribute__((ext_vector_type(16))) float f32x16;
typedef __attribute__((ext_vector_type(4))) float fvec4;

static constexpr int MTOT = 16384;   // B*S
static constexpr int KF   = 4096;    // IN_F
static constexpr int NF   = 4096;    // OUT_F
static constexpr int BM = 256, BN = 256, BK = 32;
static constexpr int TILE = BM * BK;          // 8192 bf16 elems per K-tile panel
static constexpr int KT = KF / BK;            // 128 K-tiles
static constexpr int MB = MTOT / BM;          // 64
static constexpr int NB = NF / BN;            // 16

// ---------------- prep: x -> bf16, fragment-major (32x32x16 frags) -----------
// (R4-R9 prep, verified: reads coalesce as 32 rows x full 64B lines; writes
//  are consecutive 16B per consecutive tid.)
__global__ __launch_bounds__(256) void tile_x_kernel(const float* __restrict__ x,
                                                     __hip_bfloat16* __restrict__ xt) {
    int blk = blockIdx.x;               // mb*KT + kt ; grid = 64*128
    int mb = blk >> 7, kt = blk & 127;
    int tid = threadIdx.x;
    __hip_bfloat16* dst = xt + (size_t)blk * TILE;
#pragma unroll
    for (int it = 0; it < 4; ++it) {
        int e = (it * 256 + tid) * 8;   // element within tile, 0..8191
        int f = e >> 9;                 // fragment 0..15
        int l = (e >> 3) & 63;          // lane 0..63
        int rb = f >> 1, kh = f & 1;
        int row = mb * BM + rb * 32 + (l & 31);
        int k0  = kt * BK + kh * 16 + (l >> 5) * 8;
        const fvec4* s = (const fvec4*)(x + (size_t)row * KF + k0);
        fvec4 v0 = s[0], v1 = s[1];
        union { bf16x8 v; __hip_bfloat16 h[8]; } o;
        o.h[0] = __float2bfloat16(v0[0]); o.h[1] = __float2bfloat16(v0[1]);
        o.h[2] = __float2bfloat16(v0[2]); o.h[3] = __float2bfloat16(v0[3]);
        o.h[4] = __float2bfloat16(v1[0]); o.h[5] = __float2bfloat16(v1[1]);
        o.h[6] = __float2bfloat16(v1[2]); o.h[7] = __float2bfloat16(v1[3]);
        *(bf16x8*)(dst + e) = o.v;
    }
}

// ---------------- prep: W' = W + tiled(A) -> bf16 fragment-major -------------
__global__ __launch_bounds__(256) void tile_w_kernel(const float* __restrict__ W,
                                                     const float* __restrict__ A,
                                                     __hip_bfloat16* __restrict__ wt) {
    int blk = blockIdx.x;               // nb*KT + kt ; grid = 16*128
    int nb = blk >> 7, kt = blk & 127;
    int tid = threadIdx.x;
    __hip_bfloat16* dst = wt + (size_t)blk * TILE;
#pragma unroll
    for (int it = 0; it < 4; ++it) {
        int e = (it * 256 + tid) * 8;
        int f = e >> 9;
        int l = (e >> 3) & 63;
        int rb = f >> 1, kh = f & 1;
        int o  = nb * BN + rb * 32 + (l & 31);
        int k0 = kt * BK + kh * 16 + (l >> 5) * 8;
        const fvec4* sw = (const fvec4*)(W + (size_t)o * KF + k0);
        const fvec4* sa = (const fvec4*)(A + (size_t)(o & 1023) * 1024 + (k0 & 1023));
        fvec4 w0 = sw[0], w1 = sw[1];
        fvec4 a0 = sa[0], a1 = sa[1];
        union { bf16x8 v; __hip_bfloat16 h[8]; } ov;
        ov.h[0] = __float2bfloat16(w0[0] + a0[0]); ov.h[1] = __float2bfloat16(w0[1] + a0[1]);
        ov.h[2] = __float2bfloat16(w0[2] + a0[2]); ov.h[3] = __float2bfloat16(w0[3] + a0[3]);
        ov.h[4] = __float2bfloat16(w1[0] + a1[0]); ov.h[5] = __float2bfloat16(w1[1] + a1[1]);
        ov.h[6] = __float2bfloat16(w1[2] + a1[2]); ov.h[7] = __float2bfloat16(w1[3] + a1[3]);
        *(bf16x8*)(dst + e) = ov.v;
    }
}

// ---------------- async global->LDS (width 16) ----------------
__device__ inline void gload_lds16(const __hip_bfloat16* g, __hip_bfloat16* l) {
    __builtin_amdgcn_global_load_lds(
        (const __attribute__((address_space(1))) unsigned int*)g,
        (__attribute__((address_space(3))) unsigned int*)l, 16, 0, 0);
}

// stage one K-tile (A panel + B panel) = 4 x global_load_lds_dwordx4
#define STG(tt, sl) { const __hip_bfloat16* ga = aP + (size_t)(tt) * TILE;       \
    gload_lds16(ga, As + (sl) * TILE + t8);                                      \
    gload_lds16(ga + 4096, As + (sl) * TILE + 4096 + t8);                        \
    const __hip_bfloat16* gb = bP + (size_t)(tt) * TILE;                         \
    gload_lds16(gb, Bs + (sl) * TILE + t8);                                      \
    gload_lds16(gb + 4096, Bs + (sl) * TILE + 4096 + t8); }

// read one kh-set (6 ds_read_b128) into named register set P
#define RD_KH(P, SL, KH) {                                                       \
    const __hip_bfloat16* ab_ = As + (SL) * TILE + aOff + (KH) * 512;            \
    P##a0 = *(const bf16x8*)(ab_);                                               \
    P##a1 = *(const bf16x8*)(ab_ + 1024);                                        \
    P##a2 = *(const bf16x8*)(ab_ + 2048);                                        \
    P##a3 = *(const bf16x8*)(ab_ + 3072);                                        \
    const __hip_bfloat16* bb_ = Bs + (SL) * TILE + bOff + (KH) * 512;            \
    P##b0 = *(const bf16x8*)(bb_);                                               \
    P##b1 = *(const bf16x8*)(bb_ + 1024); }

// 8 MFMAs consuming register set P
#define MM_KH(P) {                                                               \
    acc[0][0] = __builtin_amdgcn_mfma_f32_32x32x16_bf16(P##a0, P##b0, acc[0][0], 0, 0, 0); \
    acc[0][1] = __builtin_amdgcn_mfma_f32_32x32x16_bf16(P##a0, P##b1, acc[0][1], 0, 0, 0); \
    acc[1][0] = __builtin_amdgcn_mfma_f32_32x32x16_bf16(P##a1, P##b0, acc[1][0], 0, 0, 0); \
    acc[1][1] = __builtin_amdgcn_mfma_f32_32x32x16_bf16(P##a1, P##b1, acc[1][1], 0, 0, 0); \
    acc[2][0] = __builtin_amdgcn_mfma_f32_32x32x16_bf16(P##a2, P##b0, acc[2][0], 0, 0, 0); \
    acc[2][1] = __builtin_amdgcn_mfma_f32_32x32x16_bf16(P##a2, P##b1, acc[2][1], 0, 0, 0); \
    acc[3][0] = __builtin_amdgcn_mfma_f32_32x32x16_bf16(P##a3, P##b0, acc[3][0], 0, 0, 0); \
    acc[3][1] = __builtin_amdgcn_mfma_f32_32x32x16_bf16(P##a3, P##b1, acc[3][1], 0, 0, 0); }

#define SGB(m, n) __builtin_amdgcn_sched_group_barrier((m), (n), 0)

// end-of-step sync (shared by both wave groups; 4 loads issued per step ->
// vmcnt(4) drains tile t+1 before step t+1 pre-reads it)
#define STEP_END {                                                               \
    asm volatile("s_waitcnt vmcnt(4)" ::: "memory");                             \
    __builtin_amdgcn_s_barrier();                                                \
    __builtin_amdgcn_sched_barrier(0);                                           \
    asm volatile("" ::: "memory"); }

// wm=0 group: reads lead.  V4, (D M)x12, M4.
#define TILE_STEP_R(SLT, SLN, STAGE_STMT) {                                      \
    STAGE_STMT;                                                                  \
    RD_KH(B, SLT, 1)     /* read (t,kh1)  */                                     \
    MM_KH(A)             /* mfma (t,kh0)  */                                     \
    RD_KH(A, SLN, 0)     /* read (t+1,kh0)*/                                     \
    MM_KH(B)             /* mfma (t,kh1)  */                                     \
    SGB(0x30, 4);                                                                \
    SGB(0x100, 1); SGB(0x8, 1); SGB(0x100, 1); SGB(0x8, 1);                      \
    SGB(0x100, 1); SGB(0x8, 1); SGB(0x100, 1); SGB(0x8, 1);                      \
    SGB(0x100, 1); SGB(0x8, 1); SGB(0x100, 1); SGB(0x8, 1);                      \
    SGB(0x100, 1); SGB(0x8, 1); SGB(0x100, 1); SGB(0x8, 1);                      \
    SGB(0x100, 1); SGB(0x8, 1); SGB(0x100, 1); SGB(0x8, 1);                      \
    SGB(0x100, 1); SGB(0x8, 1); SGB(0x100, 1); SGB(0x8, 1);                      \
    SGB(0x8, 4);                                                                 \
    STEP_END }

// wm=1 group: MFMAs lead (consume set A read last step).  (M D)x12, M4, V4.
#define TILE_STEP_M(SLT, SLN, STAGE_STMT) {                                      \
    MM_KH(A)             /* mfma (t,kh0)  */                                     \
    RD_KH(B, SLT, 1)     /* read (t,kh1)  */                                     \
    MM_KH(B)             /* mfma (t,kh1)  */                                     \
    RD_KH(A, SLN, 0)     /* read (t+1,kh0)*/                                     \
    STAGE_STMT;                                                                  \
    SGB(0x8, 1); SGB(0x100, 1); SGB(0x8, 1); SGB(0x100, 1);                      \
    SGB(0x8, 1); SGB(0x100, 1); SGB(0x8, 1); SGB(0x100, 1);                      \
    SGB(0x8, 1); SGB(0x100, 1); SGB(0x8, 1); SGB(0x100, 1);                      \
    SGB(0x8, 1); SGB(0x100, 1); SGB(0x8, 1); SGB(0x100, 1);                      \
    SGB(0x8, 1); SGB(0x100, 1); SGB(0x8, 1); SGB(0x100, 1);                      \
    SGB(0x8, 1); SGB(0x100, 1); SGB(0x8, 1); SGB(0x100, 1);                      \
    SGB(0x8, 4);                                                                 \
    SGB(0x30, 4);                                                                \
    STEP_END }

__global__ __launch_bounds__(512, 2) void gemm_bf16_kernel(
    const __hip_bfloat16* __restrict__ xt, const __hip_bfloat16* __restrict__ wt,
    const float* __restrict__ bias, float* __restrict__ out) {
    extern __shared__ __hip_bfloat16 lds[];
    __hip_bfloat16* As = lds;                 // 4 slots * 8192 elems (64 KB)
    __hip_bfloat16* Bs = lds + 4 * TILE;      // 4 slots * 8192 elems (64 KB)

    // XCD chunking, nb-major inside chunk (B-panels L2-resident per XCD)
    int bid = blockIdx.x;                     // nwg = 1024
    int wg = (bid & 7) * 128 + (bid >> 3);
    int nb = wg >> 6;                         // 16 col-blocks
    int mb = wg & 63;                         // 64 row-blocks

    int tid = threadIdx.x;
    int lane = tid & 63;
    int wv = tid >> 6;                        // 8 waves
    int wm = wv >> 2, wn = wv & 3;            // 2 x 4 wave grid, 128x64 C each
    int t8 = tid * 8;

    int aOff = wm * 4096 + lane * 8;          // + kh*512 + fm*1024
    int bOff = wn * 2048 + lane * 8;          // + kh*512 + fn*1024

    const __hip_bfloat16* aP = xt + (size_t)mb * (KT * TILE) + t8;
    const __hip_bfloat16* bP = wt + (size_t)nb * (KT * TILE) + t8;

    f32x16 acc[4][2];
#pragma unroll
    for (int fm = 0; fm < 4; ++fm)
#pragma unroll
        for (int fn = 0; fn < 2; ++fn)
#pragma unroll
            for (int r = 0; r < 16; ++r) acc[fm][fn][r] = 0.f;

    bf16x8 Aa0, Aa1, Aa2, Aa3, Ab0, Ab1;      // kh-set A (static names)
    bf16x8 Ba0, Ba1, Ba2, Ba3, Bb0, Bb1;      // kh-set B

    // prologue: tiles 0,1,2 -> slots 0,1,2; vmcnt(4) drains tiles 0 AND 1
    STG(0, 0); STG(1, 1); STG(2, 2);
    asm volatile("s_waitcnt vmcnt(4)" ::: "memory");
    __builtin_amdgcn_s_barrier();
    asm volatile("" ::: "memory");
    RD_KH(A, 0, 0)                            // prime set A with (t=0, kh0)

    // main loop: step t computes K-tile t (slot t&3), stages tile t+3,
    // pre-reads (t+1,kh0). vmcnt(4) per step drains tile t+2.
    // wm=0: read-leading order; wm=1: MFMA-leading order -> at barrier exit
    // one group feeds the LDS port while the other feeds the matrix pipe.
    // Both groups execute identical barrier counts (legal divergence).
    if (wm == 0) {
        for (int j = 0; j < KT / 4; ++j) {
            int tb = 4 * j;
            int t4 = tb + 4; if (t4 >= KT) t4 = 0;   // tail clamp (data unused)
            int t5 = tb + 5; if (t5 >= KT) t5 = 0;
            int t6 = tb + 6; if (t6 >= KT) t6 = 0;
            TILE_STEP_R(0, 1, STG(tb + 3, 3));
            TILE_STEP_R(1, 2, STG(t4, 0));
            TILE_STEP_R(2, 3, STG(t5, 1));
            TILE_STEP_R(3, 0, STG(t6, 2));
        }
    } else {
        for (int j = 0; j < KT / 4; ++j) {
            int tb = 4 * j;
            int t4 = tb + 4; if (t4 >= KT) t4 = 0;
            int t5 = tb + 5; if (t5 >= KT) t5 = 0;
            int t6 = tb + 6; if (t6 >= KT) t6 = 0;
            TILE_STEP_M(0, 1, STG(tb + 3, 3));
            TILE_STEP_M(1, 2, STG(t4, 0));
            TILE_STEP_M(2, 3, STG(t5, 1));
            TILE_STEP_M(3, 0, STG(t6, 2));
        }
    }
    // drain all LDS-DMA before kernel end (no in-flight writes at s_endpgm)
    asm volatile("s_waitcnt vmcnt(0)" ::: "memory");

    // epilogue: 32x32 C/D layout: col = lane&31, row = (reg&3)+8*(reg>>2)+4*(lane>>5)
    int row0 = mb * BM + wm * 128;
    int col0 = nb * BN + wn * 64;
    int ln31 = lane & 31;
    int l5 = lane >> 5;
#pragma unroll
    for (int fn = 0; fn < 2; ++fn) {
        int col = col0 + fn * 32 + ln31;
        float bv = bias[col];
#pragma unroll
        for (int fm = 0; fm < 4; ++fm) {
            int rbase = row0 + fm * 32 + 4 * l5;
#pragma unroll
            for (int r = 0; r < 16; ++r) {
                int row = rbase + (r & 3) + 8 * (r >> 2);
                out[(size_t)row * NF + col] = acc[fm][fn][r] + bv;
            }
        }
    }
}

extern "C" void kernel_launch(void* const* d_in, const int* in_sizes, int n_in,
                              void* d_out, int out_size, void* d_ws, size_t ws_size,
                              hipStream_t stream) {
    const float* x = (const float*)d_in[0];
    const float* W = (const float*)d_in[1];
    const float* b = (const float*)d_in[2];
    const float* A = (const float*)d_in[3];
    float* out = (float*)d_out;

    size_t xt_elems = (size_t)MB * KT * TILE;       // 67.1M elems
    size_t wt_elems = (size_t)NB * KT * TILE;       // 16.8M elems
    size_t need = (xt_elems + wt_elems) * sizeof(__hip_bfloat16);
    if (ws_size < need) return;

    __hip_bfloat16* xt = (__hip_bfloat16*)d_ws;
    __hip_bfloat16* wt = xt + xt_elems;

    // 4 A-slots + 4 B-slots of 16 KB each = 131072 bytes (R13/R14 bug: 65536)
    (void)hipFuncSetAttribute((const void*)gemm_bf16_kernel,
                              hipFuncAttributeMaxDynamicSharedMemorySize, 131072);

    tile_x_kernel<<<MB * KT, 256, 0, stream>>>(x, xt);
    tile_w_kernel<<<NB * KT, 256, 0, stream>>>(W, A, wt);
    gemm_bf16_kernel<<<MB * NB, 512, 131072, stream>>>(xt, wt, b, out);
}